// Round 6
// baseline (334.716 us; speedup 1.0000x reference)
//
#include <hip/hip_runtime.h>
#include <hip/hip_bf16.h>
#include <math.h>

// Problem constants: B=4, C=512, N=H*W=4096, C8=64
#define BB 4
#define CC 512
#define NN 4096
#define LOG2E 1.4426950408889634f

typedef short short8 __attribute__((ext_vector_type(8)));
typedef float f32x4 __attribute__((ext_vector_type(4)));
typedef float f32x16 __attribute__((ext_vector_type(16)));

#define MFMA16(a, b, c) __builtin_amdgcn_mfma_f32_16x16x32_bf16((a), (b), (c), 0, 0, 0)
#define MFMA32(a, b, c) __builtin_amdgcn_mfma_f32_32x32x16_bf16((a), (b), (c), 0, 0, 0)

static __device__ __forceinline__ unsigned short f2bf(float f) {
    union { float f; unsigned int u; } v; v.f = f;
    unsigned int r = v.u + 0x7FFFu + ((v.u >> 16) & 1u);
    return (unsigned short)(r >> 16);
}

static __device__ __forceinline__ unsigned int pk2bf(float a, float b) {
    __hip_bfloat162 t = __float22bfloat162_rn(make_float2(a, b));
    return *(unsigned int*)&t;
}

static __device__ __forceinline__ void gload16(const void* g, void* l) {
    __builtin_amdgcn_global_load_lds(
        (const __attribute__((address_space(1))) unsigned int*)g,
        (__attribute__((address_space(3))) unsigned int*)l, 16, 0, 0);
}

// ---------------------------------------------------------------------------
// Kernel 0: W f32 -> bf16 concat [640][512]; Wb/bb pre-scaled by LOG2E.
// ---------------------------------------------------------------------------
__global__ __launch_bounds__(256) void k_wconv(
    const float* __restrict__ Wb, const float* __restrict__ bb,
    const float* __restrict__ Wc, const float* __restrict__ bc,
    const float* __restrict__ Wd, const float* __restrict__ bd,
    unsigned short* __restrict__ Wcat, float* __restrict__ bcat)
{
    int r = blockIdx.x;
    int t = threadIdx.x;
    const float* src; const float* bsrc; int bi; float scale;
    if (r < 64)       { src = Wb + (size_t)r * 512;         bsrc = bb; bi = r;       scale = LOG2E; }
    else if (r < 128) { src = Wc + (size_t)(r - 64) * 512;  bsrc = bc; bi = r - 64;  scale = 1.0f; }
    else              { src = Wd + (size_t)(r - 128) * 512; bsrc = bd; bi = r - 128; scale = 1.0f; }
    float2 v = *(const float2*)&src[t * 2];
    *(unsigned int*)&Wcat[(size_t)r * 512 + t * 2] = pk2bf(v.x * scale, v.y * scale);
    if (t == 0) bcat[r] = bsrc[bi] * scale;
}

// ---------------------------------------------------------------------------
// Kernel 1: x[b][c][n] f32  ->  xT[b][n][c] bf16   (LDS-tiled transpose)
// ---------------------------------------------------------------------------
__global__ __launch_bounds__(256) void k_transpose(
    const float* __restrict__ x, unsigned short* __restrict__ xT)
{
    __shared__ float lds[64][65];
    int bid = blockIdx.x;
    int cb = bid & 7;
    int nb = (bid >> 3) & 63;
    int b  = bid >> 9;
    int t = threadIdx.x;
    int r = t >> 4;
    int q = t & 15;

#pragma unroll
    for (int p = 0; p < 4; ++p) {
        int c = p * 16 + r;
        const float4 v = *(const float4*)&x[((size_t)(b * CC + cb * 64 + c)) * NN + nb * 64 + q * 4];
        lds[c][q * 4 + 0] = v.x;
        lds[c][q * 4 + 1] = v.y;
        lds[c][q * 4 + 2] = v.z;
        lds[c][q * 4 + 3] = v.w;
    }
    __syncthreads();
#pragma unroll
    for (int p = 0; p < 4; ++p) {
        int n = p * 16 + r;
        ushort4 o;
        o.x = f2bf(lds[q * 4 + 0][n]);
        o.y = f2bf(lds[q * 4 + 1][n]);
        o.z = f2bf(lds[q * 4 + 2][n]);
        o.w = f2bf(lds[q * 4 + 3][n]);
        *(ushort4*)&xT[((size_t)(b * NN + nb * 64 + n)) * CC + cb * 64 + q * 4] = o;
    }
}

// ---------------------------------------------------------------------------
// Kernel 2: features GEMM (bf16 W from k_wconv; Q path pre-scaled by LOG2E).
//   ob==0 -> Q[b][n][64]   ob==1 -> K[b][n][64]
//   ob>=2 -> Vtl[b][t=n/64][c][64]
// ---------------------------------------------------------------------------
__global__ __launch_bounds__(256) void k_feat(
    const unsigned short* __restrict__ xT,
    const unsigned short* __restrict__ Wcat,
    const float* __restrict__ bcat,
    unsigned short* __restrict__ Q,
    unsigned short* __restrict__ Kf,
    unsigned short* __restrict__ Vtl)
{
    int bid = blockIdx.x;
    int ob = bid % 10;
    int nb = (bid / 10) & 63;
    int b  = bid / 640;
    int t = threadIdx.x, w = t >> 6, lane = t & 63;
    int lr = lane & 15, lg = lane >> 4;

    int o_local = w * 16 + lr;
    int wr = (ob == 0) ? o_local : (ob == 1 ? 64 + o_local : 128 + (ob - 2) * 64 + o_local);
    const unsigned short* Wrow = Wcat + (size_t)wr * CC;
    const unsigned short* xrow = xT + ((size_t)(b * NN + nb * 64)) * CC;

    f32x4 acc[4] = {};

    for (int kt = 0; kt < 8; ++kt) {
        int k0 = kt * 64;
        short8 bfr[2];
#pragma unroll
        for (int ks = 0; ks < 2; ++ks)
            bfr[ks] = *(const short8*)&Wrow[k0 + ks * 32 + lg * 8];
#pragma unroll
        for (int rf = 0; rf < 4; ++rf) {
#pragma unroll
            for (int ks = 0; ks < 2; ++ks) {
                short8 a = *(const short8*)&xrow[(size_t)(rf * 16 + lr) * CC + k0 + ks * 32 + lg * 8];
                acc[rf] = MFMA16(a, bfr[ks], acc[rf]);
            }
        }
    }

    float bias = bcat[wr];
#pragma unroll
    for (int rf = 0; rf < 4; ++rf) {
        if (ob < 2) {
            unsigned short* dst = (ob == 0) ? Q : Kf;
#pragma unroll
            for (int i = 0; i < 4; ++i) {
                int n = nb * 64 + rf * 16 + lg * 4 + i;
                dst[((size_t)(b * NN + n)) * 64 + o_local] = f2bf(acc[rf][i] + bias);
            }
        } else {
            int row = (ob - 2) * 64 + o_local;          // c
            int nl = rf * 16 + lg * 4;                  // n local within tile
            ushort4 o4;
            o4.x = f2bf(acc[rf][0] + bias);
            o4.y = f2bf(acc[rf][1] + bias);
            o4.z = f2bf(acc[rf][2] + bias);
            o4.w = f2bf(acc[rf][3] + bias);
            *(ushort4*)&Vtl[(((size_t)(b * 64 + nb)) * CC + row) * 64 + nl] = o4;
        }
    }
}

// ---------------------------------------------------------------------------
// Kernel 3: flash attention v4 — in-register P, K-from-global, V-only LDS.
// grid = 4b x 64qb x 2cb = 512 blocks (2/CU), 256 thr / 4 waves.
// Wave (qi,mi): computes S^T[mi 32m][qi 32q] = mfma(K,Q) (q lane-local),
// exp2 in-reg, half-swap shfl builds PV B-frags; accumulates partial
// O[c 256][its 32q] over its 32m slice in acc[8] (128 VGPR).
// End: mi-partner reduction via reused V-LDS, then epilogue.
// One barrier per iteration; only V is LDS-staged (double-buffered).
// ---------------------------------------------------------------------------
__global__ __launch_bounds__(256, 2) void k_attn(
    const unsigned short* __restrict__ Q,
    const unsigned short* __restrict__ Kf,
    const unsigned short* __restrict__ Vtl,
    const float* __restrict__ x,
    const float* __restrict__ alpha_p,
    float* __restrict__ out)
{
    __shared__ __align__(16) char smem[2][32768];   // V tiles [c 256][m 64] bf16, dbuf
    __shared__ float Lacc[2][64];

    int bid0 = blockIdx.x;
    int bid = (bid0 & 7) * 64 + (bid0 >> 3);        // bijective XCD swizzle (512 % 8 == 0)
    int cb = bid & 1;
    int qb = (bid >> 1) & 63;
    int b  = bid >> 7;
    int tid = threadIdx.x;
    int w = tid >> 6, lane = tid & 63;
    int l31 = lane & 31, h = lane >> 5;
    int qi = w >> 1, mi = w & 1;

    const char* Vb = (const char*)Vtl + (size_t)b * (64 * 65536) + (size_t)cb * 32768;
    const unsigned short* Kb = Kf + (size_t)b * NN * 64;

    // Q B-frags: col q = qb*64 + qi*32 + l31, k d = kk*16 + h*8 + e
    short8 qfr[4];
    {
        const unsigned short* qp = Q + ((size_t)b * NN + qb * 64 + qi * 32 + l31) * 64;
#pragma unroll
        for (int kk = 0; kk < 4; ++kk)
            qfr[kk] = *(const short8*)&qp[kk * 16 + h * 8];
    }

    // Swizzled V read bases (per kk); + ct*4096 walks c-subtiles
    int vbase[2];
#pragma unroll
    for (int kk = 0; kk < 2; ++kk)
        vbase[kk] = (l31 * 128 + mi * 64 + kk * 32 + h * 16) ^ ((l31 & 7) << 4);

#define STAGE(T, BUF)                                                          \
    do {                                                                       \
        const char* vs_ = Vb + (size_t)(T) * 65536;                            \
        _Pragma("unroll")                                                      \
        for (int i_ = 0; i_ < 8; ++i_) {                                       \
            int du_ = (i_ * 4 + w) * 1024;                                     \
            int dl_ = du_ + lane * 16;                                         \
            int sl_ = dl_ ^ (((dl_ >> 7) & 7) << 4);                           \
            gload16(vs_ + sl_, &smem[BUF][0] + du_);                           \
        }                                                                      \
    } while (0)

#define KLOAD(DST, T)                                                          \
    do {                                                                       \
        const unsigned short* kp_ = Kb + ((size_t)(T) * 64 + mi * 32 + l31) * 64; \
        _Pragma("unroll")                                                      \
        for (int kk_ = 0; kk_ < 4; ++kk_)                                      \
            DST[kk_] = *(const short8*)&kp_[kk_ * 16 + h * 8];                 \
    } while (0)

    f32x16 acc[8] = {};      // O-partial: [ct 0..7] x (32c-rows x 32q)
    float lsum = 0.f;
    short8 kfA[4], kfB[4];

    STAGE(0, 0);
    KLOAD(kfA, 0);
    asm volatile("s_waitcnt vmcnt(0)" ::: "memory");
    __builtin_amdgcn_s_barrier();

#define BODY(T, BUF, KF)                                                       \
    do {                                                                       \
        f32x16 st = {};                                                        \
        __builtin_amdgcn_s_setprio(1);                                         \
        _Pragma("unroll")                                                      \
        for (int kk = 0; kk < 4; ++kk)                                         \
            st = MFMA32(KF[kk], qfr[kk], st);                                  \
        __builtin_amdgcn_s_setprio(0);                                         \
        float p[16];                                                           \
        _Pragma("unroll")                                                      \
        for (int e = 0; e < 16; ++e) {                                         \
            p[e] = __builtin_amdgcn_exp2f(st[e]);                              \
            lsum += p[e];                                                      \
        }                                                                      \
        unsigned int pk[4][2];                                                 \
        _Pragma("unroll")                                                      \
        for (int tt = 0; tt < 4; ++tt)                                         \
            _Pragma("unroll")                                                  \
            for (int pp = 0; pp < 2; ++pp)                                     \
                pk[tt][pp] = pk2bf(p[4 * tt + 2 * pp], p[4 * tt + 2 * pp + 1]);\
        short8 pfrag[2];                                                       \
        _Pragma("unroll")                                                      \
        for (int kk = 0; kk < 2; ++kk) {                                       \
            unsigned int sel0 = h ? pk[2 * kk][0] : pk[2 * kk + 1][0];         \
            unsigned int sel1 = h ? pk[2 * kk][1] : pk[2 * kk + 1][1];         \
            unsigned int r0 = __shfl_xor(sel0, 32);                            \
            unsigned int r1 = __shfl_xor(sel1, 32);                            \
            union { unsigned int u[4]; short8 s; } pa;                         \
            pa.u[0] = h ? r0 : pk[2 * kk][0];                                  \
            pa.u[1] = h ? r1 : pk[2 * kk][1];                                  \
            pa.u[2] = h ? pk[2 * kk + 1][0] : r0;                              \
            pa.u[3] = h ? pk[2 * kk + 1][1] : r1;                              \
            pfrag[kk] = pa.s;                                                  \
        }                                                                      \
        const char* vb_ = &smem[BUF][0];                                       \
        __builtin_amdgcn_s_setprio(1);                                         \
        _Pragma("unroll")                                                      \
        for (int ct = 0; ct < 8; ++ct) {                                       \
            short8 vf0 = *(const short8*)(vb_ + ct * 4096 + vbase[0]);         \
            short8 vf1 = *(const short8*)(vb_ + ct * 4096 + vbase[1]);         \
            acc[ct] = MFMA32(vf0, pfrag[0], acc[ct]);                          \
            acc[ct] = MFMA32(vf1, pfrag[1], acc[ct]);                          \
        }                                                                      \
        __builtin_amdgcn_s_setprio(0);                                         \
        asm volatile("s_waitcnt vmcnt(0)" ::: "memory");                       \
        __builtin_amdgcn_s_barrier();                                          \
    } while (0)

#pragma unroll 1
    for (int t2 = 0; t2 < 32; ++t2) {
        int t0 = t2 * 2;
        STAGE(t0 + 1, 1);
        KLOAD(kfB, t0 + 1);
        BODY(t0, 0, kfA);
        int nt = (t0 + 2 < 64) ? t0 + 2 : 63;
        STAGE(nt, 0);
        KLOAD(kfA, nt);
        BODY(t0 + 1, 1, kfB);
    }

    // ---- l totals ----
    lsum += __shfl_xor(lsum, 32);
    if (h == 0) Lacc[mi][qi * 32 + l31] = lsum;
    __syncthreads();

    // ---- mi-partner reduction through reused V-LDS (4 regions x 16 KB) ----
    float* red = (float*)&smem[0][0];
    {
        int region = qi * 2 + (1 - mi);
#pragma unroll
        for (int c2 = 0; c2 < 4; ++c2)
            *(f32x16*)(red + region * 4096 + c2 * 1024 + lane * 16) = acc[(1 - mi) * 4 + c2];
    }
    __syncthreads();

    float alpha = alpha_p[0];
    float inv = alpha / (Lacc[0][qi * 32 + l31] + Lacc[1][qi * 32 + l31]);
    int myreg = qi * 2 + mi;
#pragma unroll
    for (int c2 = 0; c2 < 4; ++c2) {
        f32x16 o = acc[mi * 4 + c2] + *(const f32x16*)(red + myreg * 4096 + c2 * 1024 + lane * 16);
        int cbase = cb * 256 + (mi * 4 + c2) * 32;
#pragma unroll
        for (int r = 0; r < 16; ++r) {
            int row = cbase + (r & 3) + 8 * (r >> 2) + 4 * h;
            size_t off = ((size_t)(b * CC + row)) * NN + qb * 64 + qi * 32 + l31;
            out[off] = x[off] + o[r] * inv;
        }
    }
#undef BODY
#undef KLOAD
#undef STAGE
}

// ---------------------------------------------------------------------------
extern "C" void kernel_launch(void* const* d_in, const int* in_sizes, int n_in,
                              void* d_out, int out_size, void* d_ws, size_t ws_size,
                              hipStream_t stream)
{
    const float* x     = (const float*)d_in[0];
    const float* Wb    = (const float*)d_in[1];
    const float* bbias = (const float*)d_in[2];
    const float* Wc    = (const float*)d_in[3];
    const float* cbias = (const float*)d_in[4];
    const float* Wd    = (const float*)d_in[5];
    const float* dbias = (const float*)d_in[6];
    const float* alpha = (const float*)d_in[7];
    float* out = (float*)d_out;

    unsigned short* xT   = (unsigned short*)d_ws;                 // 16 MB
    unsigned short* Qd   = xT + (size_t)BB * NN * CC;             //  2 MB
    unsigned short* Kd   = Qd + (size_t)BB * NN * 64;             //  2 MB
    unsigned short* Vtl  = Kd + (size_t)BB * NN * 64;             // 16 MB
    unsigned short* Wcat = Vtl + (size_t)BB * NN * CC;            // 640 KB
    float*          bcat = (float*)(Wcat + (size_t)640 * 512);    // 2.5 KB

    k_wconv<<<640, 256, 0, stream>>>(Wb, bbias, Wc, cbias, Wd, dbias, Wcat, bcat);
    k_transpose<<<2048, 256, 0, stream>>>(x, xT);
    k_feat<<<2560, 256, 0, stream>>>(xT, Wcat, bcat, Qd, Kd, Vtl);
    k_attn<<<512, 256, 0, stream>>>(Qd, Kd, Vtl, x, alpha, out);
}

// Round 7
// 279.981 us; speedup vs baseline: 1.1955x; 1.1955x over previous
//
#include <hip/hip_runtime.h>
#include <hip/hip_bf16.h>
#include <math.h>

// Problem constants: B=4, C=512, N=H*W=4096, C8=64
#define BB 4
#define CC 512
#define NN 4096
#define LOG2E 1.4426950408889634f

typedef short short8 __attribute__((ext_vector_type(8)));
typedef float f32x4 __attribute__((ext_vector_type(4)));
typedef float f32x16 __attribute__((ext_vector_type(16)));

#define MFMA16(a, b, c) __builtin_amdgcn_mfma_f32_16x16x32_bf16((a), (b), (c), 0, 0, 0)
#define MFMA32(a, b, c) __builtin_amdgcn_mfma_f32_32x32x16_bf16((a), (b), (c), 0, 0, 0)

static __device__ __forceinline__ unsigned short f2bf(float f) {
    union { float f; unsigned int u; } v; v.f = f;
    unsigned int r = v.u + 0x7FFFu + ((v.u >> 16) & 1u);
    return (unsigned short)(r >> 16);
}

static __device__ __forceinline__ unsigned int pk2bf(float a, float b) {
    __hip_bfloat162 t = __float22bfloat162_rn(make_float2(a, b));
    return *(unsigned int*)&t;
}

static __device__ __forceinline__ void gload16(const void* g, void* l) {
    __builtin_amdgcn_global_load_lds(
        (const __attribute__((address_space(1))) unsigned int*)g,
        (__attribute__((address_space(3))) unsigned int*)l, 16, 0, 0);
}

// ---------------------------------------------------------------------------
// Kernel 0: W f32 -> bf16 concat [640][512]; Wb/bb pre-scaled by LOG2E.
// ---------------------------------------------------------------------------
__global__ __launch_bounds__(256) void k_wconv(
    const float* __restrict__ Wb, const float* __restrict__ bb,
    const float* __restrict__ Wc, const float* __restrict__ bc,
    const float* __restrict__ Wd, const float* __restrict__ bd,
    unsigned short* __restrict__ Wcat, float* __restrict__ bcat)
{
    int r = blockIdx.x;
    int t = threadIdx.x;
    const float* src; const float* bsrc; int bi; float scale;
    if (r < 64)       { src = Wb + (size_t)r * 512;         bsrc = bb; bi = r;       scale = LOG2E; }
    else if (r < 128) { src = Wc + (size_t)(r - 64) * 512;  bsrc = bc; bi = r - 64;  scale = 1.0f; }
    else              { src = Wd + (size_t)(r - 128) * 512; bsrc = bd; bi = r - 128; scale = 1.0f; }
    float2 v = *(const float2*)&src[t * 2];
    *(unsigned int*)&Wcat[(size_t)r * 512 + t * 2] = pk2bf(v.x * scale, v.y * scale);
    if (t == 0) bcat[r] = bsrc[bi] * scale;
}

// ---------------------------------------------------------------------------
// Kernel 1: x[b][c][n] f32  ->  xT[b][n][c] bf16   (LDS-tiled transpose)
// ---------------------------------------------------------------------------
__global__ __launch_bounds__(256) void k_transpose(
    const float* __restrict__ x, unsigned short* __restrict__ xT)
{
    __shared__ float lds[64][65];
    int bid = blockIdx.x;
    int cb = bid & 7;
    int nb = (bid >> 3) & 63;
    int b  = bid >> 9;
    int t = threadIdx.x;
    int r = t >> 4;
    int q = t & 15;

#pragma unroll
    for (int p = 0; p < 4; ++p) {
        int c = p * 16 + r;
        const float4 v = *(const float4*)&x[((size_t)(b * CC + cb * 64 + c)) * NN + nb * 64 + q * 4];
        lds[c][q * 4 + 0] = v.x;
        lds[c][q * 4 + 1] = v.y;
        lds[c][q * 4 + 2] = v.z;
        lds[c][q * 4 + 3] = v.w;
    }
    __syncthreads();
#pragma unroll
    for (int p = 0; p < 4; ++p) {
        int n = p * 16 + r;
        ushort4 o;
        o.x = f2bf(lds[q * 4 + 0][n]);
        o.y = f2bf(lds[q * 4 + 1][n]);
        o.z = f2bf(lds[q * 4 + 2][n]);
        o.w = f2bf(lds[q * 4 + 3][n]);
        *(ushort4*)&xT[((size_t)(b * NN + nb * 64 + n)) * CC + cb * 64 + q * 4] = o;
    }
}

// ---------------------------------------------------------------------------
// Kernel 2: features GEMM, xT tile staged through LDS (was splinter loads).
//   ob==0 -> Q[b][n][64]  (LOG2E-scaled)
//   ob==1 -> Kg[b][t][kk][h][m 64][8e]  (coalesced K-frag layout for k_attn)
//   ob>=2 -> Vtl[b][t=n/64][c 512][64m]
// ---------------------------------------------------------------------------
__global__ __launch_bounds__(256, 2) void k_feat(
    const unsigned short* __restrict__ xT,
    const unsigned short* __restrict__ Wcat,
    const float* __restrict__ bcat,
    unsigned short* __restrict__ Q,
    unsigned short* __restrict__ Kg,
    unsigned short* __restrict__ Vtl)
{
    __shared__ __align__(16) unsigned short xs[64 * 512];   // 64 KB
    int bid = blockIdx.x;
    int ob = bid % 10;
    int nb = (bid / 10) & 63;
    int b  = bid / 640;
    int tid = threadIdx.x, w = tid >> 6, lane = tid & 63;
    int lr = lane & 15, lg = lane >> 4;

    // ---- stage xT[64n][512d] (bf16) with row-keyed XOR swizzle ----
    {
        const char* xbase = (const char*)(xT + ((size_t)(b * NN + nb * 64)) * CC);
#pragma unroll
        for (int i = 0; i < 16; ++i) {
            int du = i * 4096 + w * 1024;           // wave-uniform dest
            int dl = du + lane * 16;
            int row = dl >> 10, within = dl & 1023;
            gload16(xbase + row * 1024 + (within ^ ((row & 7) << 4)),
                    (char*)&xs[0] + du);
        }
    }
    asm volatile("s_waitcnt vmcnt(0)" ::: "memory");
    __syncthreads();

    int o_local = w * 16 + lr;
    int wr = (ob == 0) ? o_local : (ob == 1 ? 64 + o_local : 128 + (ob - 2) * 64 + o_local);
    const unsigned short* Wrow = Wcat + (size_t)wr * CC;

    f32x4 acc[4] = {};

    for (int kt = 0; kt < 8; ++kt) {
        short8 bfr[2];
#pragma unroll
        for (int ks = 0; ks < 2; ++ks)
            bfr[ks] = *(const short8*)&Wrow[kt * 64 + ks * 32 + lg * 8];
#pragma unroll
        for (int rf = 0; rf < 4; ++rf) {
            int row = rf * 16 + lr;
#pragma unroll
            for (int ks = 0; ks < 2; ++ks) {
                int kbyte = kt * 128 + ks * 64 + lg * 16;
                short8 a = *(const short8*)((const char*)&xs[0] + row * 1024 +
                                            (kbyte ^ ((row & 7) << 4)));
                acc[rf] = MFMA16(a, bfr[ks], acc[rf]);
            }
        }
    }

    float bias = bcat[wr];
#pragma unroll
    for (int rf = 0; rf < 4; ++rf) {
        if (ob == 0) {
#pragma unroll
            for (int i = 0; i < 4; ++i) {
                int n = nb * 64 + rf * 16 + lg * 4 + i;
                Q[((size_t)(b * NN + n)) * 64 + o_local] = f2bf(acc[rf][i] + bias);
            }
        } else if (ob == 1) {
            int d = o_local;
            size_t base = ((((size_t)(b * 64 + nb) * 4 + (d >> 4)) * 2 + ((d >> 3) & 1)) * 64) * 8 + (d & 7);
#pragma unroll
            for (int i = 0; i < 4; ++i) {
                int m = rf * 16 + lg * 4 + i;
                Kg[base + (size_t)m * 8] = f2bf(acc[rf][i] + bias);
            }
        } else {
            int row = (ob - 2) * 64 + o_local;          // c
            int nl = rf * 16 + lg * 4;                  // m within tile
            ushort4 o4;
            o4.x = f2bf(acc[rf][0] + bias);
            o4.y = f2bf(acc[rf][1] + bias);
            o4.z = f2bf(acc[rf][2] + bias);
            o4.w = f2bf(acc[rf][3] + bias);
            *(ushort4*)&Vtl[(((size_t)(b * 64 + nb)) * CC + row) * 64 + nl] = o4;
        }
    }
}

// ---------------------------------------------------------------------------
// Kernel 3: flash attention v5 — in-register P, coalesced K (Kg), V-only LDS.
// grid = 4b x 64qb x 2cb = 512 blocks (2/CU), 256 thr / 4 waves (qi2 x mi2).
// Wave: S^T[mi 32m][qi 32q] = mfma(K,Q); exp2 in-reg; half-swap -> P A-frags;
// PV: acc[8 ct] = P[32q] x V[its 32m][256c] partials (C[q][c], col=c).
// End: static-indexed mi-exchange via LDS reuse; float4 epilogue.
// ---------------------------------------------------------------------------
__global__ __launch_bounds__(256, 2) void k_attn(
    const unsigned short* __restrict__ Q,
    const unsigned short* __restrict__ Kg,
    const unsigned short* __restrict__ Vtl,
    const float* __restrict__ x,
    const float* __restrict__ alpha_p,
    float* __restrict__ out)
{
    __shared__ __align__(16) char smem[2][32768];   // V dbuf: [256c][64m] bf16
    __shared__ float Lacc[2][64];

    int bid0 = blockIdx.x;
    int bid = (bid0 & 7) * 64 + (bid0 >> 3);        // bijective XCD swizzle
    int cb = bid & 1;
    int qb = (bid >> 1) & 63;
    int b  = bid >> 7;
    int tid = threadIdx.x;
    int w = tid >> 6, lane = tid & 63;
    int l31 = lane & 31, h = lane >> 5;
    int qi = w >> 1, mi = w & 1;

    const char* Vb = (const char*)Vtl + (size_t)b * (64 * 65536) + (size_t)cb * 32768;
    const unsigned short* Kb = Kg + (size_t)b * 64 * 4096;

    // Q B-frags: col q = qb*64 + qi*32 + l31, k d = kk*16 + h*8 + e
    short8 qfr[4];
    {
        const unsigned short* qp = Q + ((size_t)b * NN + qb * 64 + qi * 32 + l31) * 64;
#pragma unroll
        for (int kk = 0; kk < 4; ++kk)
            qfr[kk] = *(const short8*)&qp[kk * 16 + h * 8];
    }

    // Swizzled V read bases: row c = ct*32 + l31 -> ct*4096 + pb[kk]
    int pb[2];
#pragma unroll
    for (int kk = 0; kk < 2; ++kk)
        pb[kk] = (l31 * 128 + mi * 64 + kk * 32 + h * 16) ^ ((l31 & 7) << 4);

#define STAGE(T, BUF)                                                          \
    do {                                                                       \
        const char* vs_ = Vb + (size_t)(T) * 65536;                            \
        _Pragma("unroll")                                                      \
        for (int i_ = 0; i_ < 8; ++i_) {                                       \
            int du_ = (i_ * 4 + w) * 1024;                                     \
            int dl_ = du_ + lane * 16;                                         \
            int sl_ = dl_ ^ (((dl_ >> 7) & 7) << 4);                           \
            gload16(vs_ + sl_, &smem[BUF][0] + du_);                           \
        }                                                                      \
    } while (0)

    // K frags, coalesced: lane addr = base(t,kk) + h*1024 + (mi*32+l31)*16 B
#define KLOAD(DST, T)                                                          \
    do {                                                                       \
        const unsigned short* kp_ = Kb + (size_t)(T) * 4096 +                  \
            (size_t)(h) * 512 + (size_t)(mi * 32 + l31) * 8;                   \
        _Pragma("unroll")                                                      \
        for (int kk_ = 0; kk_ < 4; ++kk_)                                      \
            DST[kk_] = *(const short8*)&kp_[kk_ * 1024];                       \
    } while (0)

    f32x16 acc[8] = {};      // [ct 0..7]: C[32q rows][32c cols]
    float lsum = 0.f;
    short8 kfA[4], kfB[4];

    STAGE(0, 0);
    KLOAD(kfA, 0);
    asm volatile("s_waitcnt vmcnt(0)" ::: "memory");
    __builtin_amdgcn_s_barrier();

#define BODY(BUF, KF)                                                          \
    do {                                                                       \
        f32x16 st = {};                                                        \
        __builtin_amdgcn_s_setprio(1);                                         \
        _Pragma("unroll")                                                      \
        for (int kk = 0; kk < 4; ++kk)                                         \
            st = MFMA32(KF[kk], qfr[kk], st);                                  \
        __builtin_amdgcn_s_setprio(0);                                         \
        float p[16];                                                           \
        _Pragma("unroll")                                                      \
        for (int e = 0; e < 16; ++e) {                                         \
            p[e] = __builtin_amdgcn_exp2f(st[e]);                              \
            lsum += p[e];                                                      \
        }                                                                      \
        unsigned int pk[4][2];                                                 \
        _Pragma("unroll")                                                      \
        for (int tt = 0; tt < 4; ++tt)                                         \
            _Pragma("unroll")                                                  \
            for (int pp = 0; pp < 2; ++pp)                                     \
                pk[tt][pp] = pk2bf(p[4 * tt + 2 * pp], p[4 * tt + 2 * pp + 1]);\
        short8 pfrag[2];                                                       \
        _Pragma("unroll")                                                      \
        for (int kk = 0; kk < 2; ++kk) {                                       \
            unsigned int sel0 = h ? pk[2 * kk][0] : pk[2 * kk + 1][0];         \
            unsigned int sel1 = h ? pk[2 * kk][1] : pk[2 * kk + 1][1];         \
            unsigned int r0 = __shfl_xor(sel0, 32);                            \
            unsigned int r1 = __shfl_xor(sel1, 32);                            \
            union { unsigned int u[4]; short8 s; } pa;                         \
            pa.u[0] = h ? r0 : pk[2 * kk][0];                                  \
            pa.u[1] = h ? r1 : pk[2 * kk][1];                                  \
            pa.u[2] = h ? pk[2 * kk + 1][0] : r0;                              \
            pa.u[3] = h ? pk[2 * kk + 1][1] : r1;                              \
            pfrag[kk] = pa.s;                                                  \
        }                                                                      \
        const char* vb_ = &smem[BUF][0];                                       \
        __builtin_amdgcn_s_setprio(1);                                         \
        _Pragma("unroll")                                                      \
        for (int ct = 0; ct < 8; ++ct) {                                       \
            short8 vf0 = *(const short8*)(vb_ + ct * 4096 + pb[0]);            \
            short8 vf1 = *(const short8*)(vb_ + ct * 4096 + pb[1]);            \
            acc[ct] = MFMA32(pfrag[0], vf0, acc[ct]);                          \
            acc[ct] = MFMA32(pfrag[1], vf1, acc[ct]);                          \
        }                                                                      \
        __builtin_amdgcn_s_setprio(0);                                         \
        asm volatile("s_waitcnt vmcnt(0)" ::: "memory");                       \
        __builtin_amdgcn_s_barrier();                                          \
    } while (0)

#pragma unroll 1
    for (int t2 = 0; t2 < 32; ++t2) {
        int t0 = t2 * 2;
        STAGE(t0 + 1, 1);
        KLOAD(kfB, t0 + 1);
        BODY(0, kfA);
        int nt = (t0 + 2 < 64) ? t0 + 2 : 63;
        STAGE(nt, 0);
        KLOAD(kfA, nt);
        BODY(1, kfB);
    }

    // ---- l totals: h-halves then mi-halves (via Lacc) ----
    lsum += __shfl_xor(lsum, 32);
    if (h == 0) Lacc[mi][qi * 32 + l31] = lsum;

    // ---- mi-exchange of partner-half acc via reused V-LDS (static idx) ----
    float* red = (float*)&smem[0][0];
    __syncthreads();
    {
        int region = qi * 2 + (1 - mi);              // partner reads this
        float* dst = red + region * 4096 + lane * 16;
        if (mi == 0) {
#pragma unroll
            for (int c2 = 0; c2 < 4; ++c2) *(f32x16*)(dst + c2 * 1024) = acc[4 + c2];
        } else {
#pragma unroll
            for (int c2 = 0; c2 < 4; ++c2) *(f32x16*)(dst + c2 * 1024) = acc[c2];
        }
    }
    __syncthreads();

    float alpha = alpha_p[0];
    const float* srcr = red + (qi * 2 + mi) * 4096 + lane * 16;
#pragma unroll
    for (int c2 = 0; c2 < 4; ++c2) {
        f32x16 o = (mi == 0 ? acc[c2] : acc[4 + c2]) + *(const f32x16*)(srcr + c2 * 1024);
        int ctg = mi * 4 + c2;
        int c = cb * 256 + ctg * 32 + l31;
#pragma unroll
        for (int rg = 0; rg < 4; ++rg) {
            int qloc = qi * 32 + rg * 8 + h * 4;
            float4 l0 = *(const float4*)&Lacc[0][qloc];
            float4 l1 = *(const float4*)&Lacc[1][qloc];
            float4 inv;
            inv.x = alpha / (l0.x + l1.x);
            inv.y = alpha / (l0.y + l1.y);
            inv.z = alpha / (l0.z + l1.z);
            inv.w = alpha / (l0.w + l1.w);
            size_t off = ((size_t)(b * CC + c)) * NN + qb * 64 + qloc;
            float4 xv = *(const float4*)&x[off];
            float4 ov;
            ov.x = xv.x + o[rg * 4 + 0] * inv.x;
            ov.y = xv.y + o[rg * 4 + 1] * inv.y;
            ov.z = xv.z + o[rg * 4 + 2] * inv.z;
            ov.w = xv.w + o[rg * 4 + 3] * inv.w;
            *(float4*)&out[off] = ov;
        }
    }
#undef BODY
#undef KLOAD
#undef STAGE
}

// ---------------------------------------------------------------------------
extern "C" void kernel_launch(void* const* d_in, const int* in_sizes, int n_in,
                              void* d_out, int out_size, void* d_ws, size_t ws_size,
                              hipStream_t stream)
{
    const float* x     = (const float*)d_in[0];
    const float* Wb    = (const float*)d_in[1];
    const float* bbias = (const float*)d_in[2];
    const float* Wc    = (const float*)d_in[3];
    const float* cbias = (const float*)d_in[4];
    const float* Wd    = (const float*)d_in[5];
    const float* dbias = (const float*)d_in[6];
    const float* alpha = (const float*)d_in[7];
    float* out = (float*)d_out;

    unsigned short* xT   = (unsigned short*)d_ws;                 // 16 MB
    unsigned short* Qd   = xT + (size_t)BB * NN * CC;             //  2 MB
    unsigned short* Kgd  = Qd + (size_t)BB * NN * 64;             //  2 MB
    unsigned short* Vtl  = Kgd + (size_t)BB * NN * 64;            // 16 MB
    unsigned short* Wcat = Vtl + (size_t)BB * NN * CC;            // 640 KB
    float*          bcat = (float*)(Wcat + (size_t)640 * 512);    // 2.5 KB

    k_wconv<<<640, 256, 0, stream>>>(Wb, bbias, Wc, cbias, Wd, dbias, Wcat, bcat);
    k_transpose<<<2048, 256, 0, stream>>>(x, xT);
    k_feat<<<2560, 256, 0, stream>>>(xT, Wcat, bcat, Qd, Kgd, Vtl);
    k_attn<<<512, 256, 0, stream>>>(Qd, Kgd, Vtl, x, alpha, out);
}